// Round 3
// baseline (722.193 us; speedup 1.0000x reference)
//
#include <hip/hip_runtime.h>
#include <hip/hip_bf16.h>
#include <cstdint>
#include <cstddef>

#define H    50
#define G4   200      // 4*H gates
#define TT   256      // timesteps
#define BATCH 512
#define KDIM 144      // layer-0 input dim
#define ODIM 144      // FC output dim

__device__ __forceinline__ float sigm(float x) {
    return 1.0f / (1.0f + __expf(-x));
}
__device__ __forceinline__ float tanhx(float x) {
    float e = __expf(2.0f * x);
    return 1.0f - 2.0f / (e + 1.0f);
}

// ---------------- Kernel 1: XP[M,200] = X[M,144] @ W_ih0^T  (W_ih0: [200,144]) -------
// BM=64, BN=64, BK=16, 256 thr, 4x4 tile, register double-buffer on the staging loads.
#define BM 64
#define BN 64
#define BK 16
__global__ __launch_bounds__(256) void xproj_gemm(
    const float* __restrict__ X, const float* __restrict__ W, float* __restrict__ XP)
{
    __shared__ float Xs[BK][BM + 4];
    __shared__ float Ws[BK][BN + 4];
    const int tid = threadIdx.x;
    const int m0 = blockIdx.x * BM;
    const int n0 = blockIdx.y * BN;
    const int kk = tid & 15;          // staging: k within tile
    const int rr = tid >> 4;          // staging: row group
    const int nt = tid & 15;          // compute: n-thread
    const int mt = tid >> 4;          // compute: m-thread
    float xr[4], wr[4];
    #pragma unroll
    for (int i = 0; i < 4; ++i) {
        xr[i] = X[(size_t)(m0 + rr + i * 16) * KDIM + kk];
        const int n = n0 + rr + i * 16;
        wr[i] = (n < G4) ? W[(size_t)n * KDIM + kk] : 0.0f;
    }
    float acc[4][4] = {};
    for (int k0 = 0; k0 < KDIM; k0 += BK) {
        #pragma unroll
        for (int i = 0; i < 4; ++i) {
            Xs[kk][rr + i * 16] = xr[i];
            Ws[kk][rr + i * 16] = wr[i];
        }
        __syncthreads();
        if (k0 + BK < KDIM) {   // prefetch next tile; overlaps the FMA loop below
            #pragma unroll
            for (int i = 0; i < 4; ++i) {
                xr[i] = X[(size_t)(m0 + rr + i * 16) * KDIM + k0 + BK + kk];
                const int n = n0 + rr + i * 16;
                wr[i] = (n < G4) ? W[(size_t)n * KDIM + k0 + BK + kk] : 0.0f;
            }
        }
        #pragma unroll
        for (int k = 0; k < BK; ++k) {
            const float4 a  = *(const float4*)&Xs[k][mt * 4];
            const float4 bb = *(const float4*)&Ws[k][nt * 4];
            const float av[4] = {a.x, a.y, a.z, a.w};
            const float bv[4] = {bb.x, bb.y, bb.z, bb.w};
            #pragma unroll
            for (int i = 0; i < 4; ++i)
                #pragma unroll
                for (int j = 0; j < 4; ++j)
                    acc[i][j] += av[i] * bv[j];
        }
        __syncthreads();
    }
    const int n = n0 + nt * 4;
    if (n + 3 < G4) {
        #pragma unroll
        for (int i = 0; i < 4; ++i) {
            const int m = m0 + mt * 4 + i;
            *(float4*)&XP[(size_t)m * G4 + n] =
                make_float4(acc[i][0], acc[i][1], acc[i][2], acc[i][3]);
        }
    }
}

// ---------------- Kernel 2: persistent 2-rows-per-WG 2-layer LSTM + fused FC --------
// 256 WGs x 384 threads (6 waves). Matrix-split groups:
//   grp0 = waves 0,1 (tid<128):  W_hh0 rows (gt, gt+100)   -> writes gs0
//   grp1 = waves 2,3:            W_ih1 rows                 -> writes gs1i (incl bias1)
//   grp2 = waves 4,5:            W_hh1 rows                 -> writes gs1h
// 100 weight VGPRs/thread (no remat), h stored as packed row-pairs hp[2k+row] so one
// b128 read feeds 8 FMA. Stage B: wave0/1 = layer0 rowA/B (c0), wave2/3 = layer1 (c1).
// Layer 1 lags one step (2 barriers/step).
__global__ __launch_bounds__(384, 2) void lstm_persist(
    const float* __restrict__ XP,
    const float* __restrict__ Whh0,
    const float* __restrict__ Wih1,
    const float* __restrict__ Whh1,
    const float* __restrict__ bih0, const float* __restrict__ bhh0,
    const float* __restrict__ bih1, const float* __restrict__ bhh1,
    const float* __restrict__ Wfc,  const float* __restrict__ bfc,
    float* __restrict__ out)
{
    const int b0   = blockIdx.x * 2;
    const int tid  = threadIdx.x;
    const int grp  = tid >> 7;        // 0,1,2
    const int gt   = tid & 127;
    const bool act = gt < 100;
    const int ga   = act ? gt : 99;
    const int gb   = ga + 100;
    const int wave = tid >> 6;        // 0..5
    const int lane = tid & 63;

    __shared__ __align__(16) float hp0[104];   // hp0[2k+r] = h0[row r][k]
    __shared__ __align__(16) float hp1[104];
    __shared__ float gs0[2][G4];
    __shared__ float gs1i[2][G4];
    __shared__ float gs1h[2][G4];
    __shared__ float h1f[2][52];

    const float* Wsel = (grp == 0) ? Whh0 : (grp == 1) ? Wih1 : Whh1;
    float wA[H], wB[H];
    #pragma unroll
    for (int k = 0; k < H; ++k) {
        wA[k] = Wsel[(size_t)ga * H + k];
        wB[k] = Wsel[(size_t)gb * H + k];
    }
    float biasA = 0.0f, biasB = 0.0f;
    if (grp == 0) { biasA = bih0[ga] + bhh0[ga]; biasB = bih0[gb] + bhh0[gb]; }
    if (grp == 1) { biasA = bih1[ga] + bhh1[ga]; biasB = bih1[gb] + bhh1[gb]; }

    if (tid < 104) { hp0[tid] = 0.0f; hp1[tid] = 0.0f; }
    float c0 = 0.0f, c1 = 0.0f;   // c0 in waves 0/1 lanes<50; c1 in waves 2/3
    __syncthreads();

    const float* xpA = XP + (size_t)(b0 + 0) * (TT * G4);
    const float* xpB = XP + (size_t)(b0 + 1) * (TT * G4);
    const bool ldx = (grp == 0) && act;
    float xaA = 0.f, xaB = 0.f, xbA = 0.f, xbB = 0.f;   // xp for (gate a/b, row A/B)
    if (ldx) {
        xaA = xpA[ga]; xaB = xpB[ga]; xbA = xpA[gb]; xbB = xpB[gb];
    }
    const float* hps = (grp == 2) ? hp1 : hp0;

    for (int t = 0; t < TT; ++t) {
        float naA = 0.f, naB = 0.f, nbA = 0.f, nbB = 0.f;
        if (ldx && t < TT - 1) {
            const size_t o = (size_t)(t + 1) * G4;
            naA = xpA[o + ga]; naB = xpB[o + ga]; nbA = xpA[o + gb]; nbB = xpB[o + gb];
        }
        // ---- stage A: grp0 -> gates0(t); grp1/2 -> gates1(t-1) partials
        float vaA = biasA + xaA, vaB = biasA + xaB;
        float vbA = biasB + xbA, vbB = biasB + xbB;
        #pragma unroll
        for (int j = 0; j < 25; ++j) {
            const float4 p = *(const float4*)&hps[j * 4];   // {A[2j],B[2j],A[2j+1],B[2j+1]}
            vaA += wA[2*j] * p.x;  vaB += wA[2*j] * p.y;
            vaA += wA[2*j+1] * p.z; vaB += wA[2*j+1] * p.w;
            vbA += wB[2*j] * p.x;  vbB += wB[2*j] * p.y;
            vbA += wB[2*j+1] * p.z; vbB += wB[2*j+1] * p.w;
        }
        if (act) {
            float (*gsx)[G4] = (grp == 0) ? gs0 : (grp == 1) ? gs1i : gs1h;
            gsx[0][ga] = vaA; gsx[1][ga] = vaB;
            gsx[0][gb] = vbA; gsx[1][gb] = vbB;
        }
        __syncthreads();
        // ---- stage B
        if (wave < 2) {
            if (lane < H) {
                const int r = wave;
                const float gi = sigm(gs0[r][lane]);
                const float gf = sigm(gs0[r][H + lane]);
                const float gg = tanhx(gs0[r][2*H + lane]);
                const float go = sigm(gs0[r][3*H + lane]);
                c0 = gf * c0 + gi * gg;
                hp0[2 * lane + r] = go * tanhx(c0);
            }
        } else if (wave < 4 && t > 0) {
            if (lane < H) {
                const int r = wave - 2;
                const float qi = sigm(gs1i[r][lane]       + gs1h[r][lane]);
                const float qf = sigm(gs1i[r][H + lane]   + gs1h[r][H + lane]);
                const float qg = tanhx(gs1i[r][2*H + lane] + gs1h[r][2*H + lane]);
                const float qo = sigm(gs1i[r][3*H + lane]  + gs1h[r][3*H + lane]);
                c1 = qf * c1 + qi * qg;
                hp1[2 * lane + r] = qo * tanhx(c1);
            }
        }
        __syncthreads();
        xaA = naA; xaB = naB; xbA = nbA; xbB = nbB;
    }
    // ---- pipeline tail: gates1(TT-1) partials (grp1/2), then layer1 update
    {
        float vaA = biasA, vaB = biasA, vbA = biasB, vbB = biasB;
        #pragma unroll
        for (int j = 0; j < 25; ++j) {
            const float4 p = *(const float4*)&hps[j * 4];
            vaA += wA[2*j] * p.x;  vaB += wA[2*j] * p.y;
            vaA += wA[2*j+1] * p.z; vaB += wA[2*j+1] * p.w;
            vbA += wB[2*j] * p.x;  vbB += wB[2*j] * p.y;
            vbA += wB[2*j+1] * p.z; vbB += wB[2*j+1] * p.w;
        }
        if (act && grp != 0) {
            float (*gsx)[G4] = (grp == 1) ? gs1i : gs1h;
            gsx[0][ga] = vaA; gsx[1][ga] = vaB;
            gsx[0][gb] = vbA; gsx[1][gb] = vbB;
        }
        __syncthreads();
        if (wave >= 2 && wave < 4 && lane < H) {
            const int r = wave - 2;
            const float qi = sigm(gs1i[r][lane]        + gs1h[r][lane]);
            const float qf = sigm(gs1i[r][H + lane]    + gs1h[r][H + lane]);
            const float qg = tanhx(gs1i[r][2*H + lane] + gs1h[r][2*H + lane]);
            const float qo = sigm(gs1i[r][3*H + lane]  + gs1h[r][3*H + lane]);
            c1 = qf * c1 + qi * qg;
            h1f[r][lane] = qo * tanhx(c1);
        }
        __syncthreads();
    }
    // ---- fused FC on the final hidden states
    if (tid < 2 * ODIM) {
        const int r = (tid >= ODIM);
        const int o = tid - r * ODIM;
        float s = bfc[o];
        #pragma unroll
        for (int k = 0; k < H; k += 2) {
            const float2 w = *(const float2*)&Wfc[(size_t)o * H + k];
            s += w.x * h1f[r][k] + w.y * h1f[r][k + 1];
        }
        out[(size_t)(b0 + r) * ODIM + o] = s;
    }
}

extern "C" void kernel_launch(void* const* d_in, const int* in_sizes, int n_in,
                              void* d_out, int out_size, void* d_ws, size_t ws_size,
                              hipStream_t stream) {
    const float* x    = (const float*)d_in[0];
    const float* wih0 = (const float*)d_in[1];
    const float* whh0 = (const float*)d_in[2];
    const float* bih0 = (const float*)d_in[3];
    const float* bhh0 = (const float*)d_in[4];
    const float* wih1 = (const float*)d_in[5];
    const float* whh1 = (const float*)d_in[6];
    const float* bih1 = (const float*)d_in[7];
    const float* bhh1 = (const float*)d_in[8];
    const float* wfc  = (const float*)d_in[9];
    const float* bfc  = (const float*)d_in[10];
    float* outp = (float*)d_out;
    float* XP = (float*)d_ws;   // 131072 x 200 fp32 = 104.86 MB scratch

    dim3 g1(BATCH * TT / BM, (G4 + BN - 1) / BN);   // (2048, 4)
    xproj_gemm<<<g1, 256, 0, stream>>>(x, wih0, XP);
    lstm_persist<<<BATCH / 2, 384, 0, stream>>>(XP, whh0, wih1, whh1,
                                                bih0, bhh0, bih1, bhh1,
                                                wfc, bfc, outp);
}

// Round 4
// 523.363 us; speedup vs baseline: 1.3799x; 1.3799x over previous
//
#include <hip/hip_runtime.h>
#include <hip/hip_bf16.h>
#include <cstdint>
#include <cstddef>

#define H    50
#define G4   200      // 4*H gates
#define TT   256      // timesteps
#define BATCH 512
#define KDIM 144      // layer-0 input dim
#define ODIM 144      // FC output dim

typedef __attribute__((ext_vector_type(8))) short short8;
typedef __attribute__((ext_vector_type(4))) float floatx4;

__device__ __forceinline__ float sigm(float x) {
    return 1.0f / (1.0f + __expf(-x));
}
__device__ __forceinline__ float tanhx(float x) {
    float e = __expf(2.0f * x);
    return 1.0f - 2.0f / (e + 1.0f);
}
__device__ __forceinline__ short bfhi(float x) {
    __hip_bfloat16 h = __float2bfloat16(x);   // RN rounding
    return __builtin_bit_cast(short, h);
}
__device__ __forceinline__ float bf2f(short s) {
    unsigned int u = ((unsigned int)(unsigned short)s) << 16;
    return __builtin_bit_cast(float, u);
}

// ---------------- Kernel 1: XP[M,200] = X[M,144] @ W_ih0^T  (fp32 VALU, unchanged) ---
#define BM 64
#define BN 64
#define BK 16
__global__ __launch_bounds__(256) void xproj_gemm(
    const float* __restrict__ X, const float* __restrict__ W, float* __restrict__ XP)
{
    __shared__ float Xs[BK][BM + 4];
    __shared__ float Ws[BK][BN + 4];
    const int tid = threadIdx.x;
    const int m0 = blockIdx.x * BM;
    const int n0 = blockIdx.y * BN;
    const int kk = tid & 15;
    const int rr = tid >> 4;
    const int nt = tid & 15;
    const int mt = tid >> 4;
    float xr[4], wr[4];
    #pragma unroll
    for (int i = 0; i < 4; ++i) {
        xr[i] = X[(size_t)(m0 + rr + i * 16) * KDIM + kk];
        const int n = n0 + rr + i * 16;
        wr[i] = (n < G4) ? W[(size_t)n * KDIM + kk] : 0.0f;
    }
    float acc[4][4] = {};
    for (int k0 = 0; k0 < KDIM; k0 += BK) {
        #pragma unroll
        for (int i = 0; i < 4; ++i) {
            Xs[kk][rr + i * 16] = xr[i];
            Ws[kk][rr + i * 16] = wr[i];
        }
        __syncthreads();
        if (k0 + BK < KDIM) {
            #pragma unroll
            for (int i = 0; i < 4; ++i) {
                xr[i] = X[(size_t)(m0 + rr + i * 16) * KDIM + k0 + BK + kk];
                const int n = n0 + rr + i * 16;
                wr[i] = (n < G4) ? W[(size_t)n * KDIM + k0 + BK + kk] : 0.0f;
            }
        }
        #pragma unroll
        for (int k = 0; k < BK; ++k) {
            const float4 a  = *(const float4*)&Xs[k][mt * 4];
            const float4 bb = *(const float4*)&Ws[k][nt * 4];
            const float av[4] = {a.x, a.y, a.z, a.w};
            const float bv[4] = {bb.x, bb.y, bb.z, bb.w};
            #pragma unroll
            for (int i = 0; i < 4; ++i)
                #pragma unroll
                for (int j = 0; j < 4; ++j)
                    acc[i][j] += av[i] * bv[j];
        }
        __syncthreads();
    }
    const int n = n0 + nt * 4;
    if (n + 3 < G4) {
        #pragma unroll
        for (int i = 0; i < 4; ++i) {
            const int m = m0 + mt * 4 + i;
            *(float4*)&XP[(size_t)m * G4 + n] =
                make_float4(acc[i][0], acc[i][1], acc[i][2], acc[i][3]);
        }
    }
}

// ---------------- Kernel 2: MFMA recurrence, 256 WGs x 512 threads (8 waves) --------
// Wcat[640x64] (zero-padded): rows 0-199 W_hh0 | 200-399 W_ih1 | 400-599 W_hh1, K=50.
// bf16 hi/lo split, 3 MFMAs (hi*hi + hi*lo + lo*hi) per tile*kstep ~= fp32 accuracy.
// Per wave: 5 M-tiles of 16 rows, A-frags resident in VGPRs (80 regs, loaded once).
// B cols: 0/1 = h0(t-1) rowA/B, 2/3 = h1(t-2) rowA/B. C layout (HW-verified m89):
// col=lane&15, row=(lane>>4)*4+reg. Stage B (tid<200) applies activations, updates
// c in registers, writes new h (bf16 hi/lo) back into the B fragment arrays.
__global__ __launch_bounds__(512, 2) void lstm_mfma(
    const float* __restrict__ XP,
    const float* __restrict__ Whh0,
    const float* __restrict__ Wih1,
    const float* __restrict__ Whh1,
    const float* __restrict__ bih0, const float* __restrict__ bhh0,
    const float* __restrict__ bih1, const float* __restrict__ bhh1,
    const float* __restrict__ Wfc,  const float* __restrict__ bfc,
    float* __restrict__ out)
{
    const int b0   = blockIdx.x * 2;
    const int tid  = threadIdx.x;
    const int lane = tid & 63;
    const int wv   = tid >> 6;        // 0..7
    const int mrow = lane & 15;       // A row within tile / B col / C col
    const int q    = lane >> 4;       // 0..3

    __shared__ __align__(16) short Bhi[16][72];   // B frag store: [n][k], 144B row stride
    __shared__ __align__(16) short Blo[16][72];
    __shared__ __align__(16) float gcat[4][640];  // C spill: [col n][gate row]
    __shared__ float h1f[2][52];

    // ---- build resident A fragments (once) ----
    short8 Ahi[5][2], Alo[5][2];
    #pragma unroll
    for (int i = 0; i < 5; ++i) {
        const int r = (wv * 5 + i) * 16 + mrow;
        const float* wrow = nullptr;
        if (r < 200)      wrow = Whh0 + (size_t)r * H;
        else if (r < 400) wrow = Wih1 + (size_t)(r - 200) * H;
        else if (r < 600) wrow = Whh1 + (size_t)(r - 400) * H;
        #pragma unroll
        for (int s = 0; s < 2; ++s) {
            #pragma unroll
            for (int j = 0; j < 8; ++j) {
                const int k = s * 32 + q * 8 + j;
                const float v = (wrow != nullptr && k < H) ? wrow[k] : 0.0f;
                const short hh = bfhi(v);
                Ahi[i][s][j] = hh;
                Alo[i][s][j] = bfhi(v - bf2f(hh));
            }
        }
    }
    // ---- zero B fragment arrays (h starts at 0; k>=50 stays 0 forever) ----
    for (int idx = tid; idx < 16 * 72; idx += 512) {
        ((short*)Bhi)[idx] = 0;
        ((short*)Blo)[idx] = 0;
    }
    // ---- stage-B thread state ----
    const bool upd = tid < G4;
    const int L  = tid / 100;             // layer (valid when upd)
    const int rw = (tid % 100) / 50;      // batch row within pair
    const int kk = tid % 50;              // hidden index
    const int ncol = 2 * L + rw;          // B column owned
    float bi = 0.f, bff = 0.f, bg = 0.f, bo = 0.f;
    if (upd) {
        const float* bA = L ? bih1 : bih0;
        const float* bB = L ? bhh1 : bhh0;
        bi  = bA[kk]         + bB[kk];
        bff = bA[H + kk]     + bB[H + kk];
        bg  = bA[2 * H + kk] + bB[2 * H + kk];
        bo  = bA[3 * H + kk] + bB[3 * H + kk];
    }
    const float* xpb = XP + (size_t)(b0 + rw) * TT * G4;
    const bool lx = upd && (L == 0);
    float xi = 0.f, xf = 0.f, xg = 0.f, xo = 0.f;
    if (lx) {   // prefetch xp(t=0)
        xi = xpb[kk]; xf = xpb[H + kk]; xg = xpb[2 * H + kk]; xo = xpb[3 * H + kk];
    }
    float c = 0.0f;     // c0 for L==0 threads, c1 for L==1 threads
    __syncthreads();

    for (int t = 0; t < TT; ++t) {
        // ---- stage A: one MFMA pass over all 3 matrices, both rows ----
        floatx4 acc[5];
        #pragma unroll
        for (int i = 0; i < 5; ++i) acc[i] = (floatx4)(0.0f);
        #pragma unroll
        for (int s = 0; s < 2; ++s) {
            const short8 bh = *(const short8*)&Bhi[mrow][s * 32 + q * 8];
            const short8 bl = *(const short8*)&Blo[mrow][s * 32 + q * 8];
            #pragma unroll
            for (int i = 0; i < 5; ++i) {
                acc[i] = __builtin_amdgcn_mfma_f32_16x16x32_bf16(Ahi[i][s], bh, acc[i], 0, 0, 0);
                acc[i] = __builtin_amdgcn_mfma_f32_16x16x32_bf16(Ahi[i][s], bl, acc[i], 0, 0, 0);
                acc[i] = __builtin_amdgcn_mfma_f32_16x16x32_bf16(Alo[i][s], bh, acc[i], 0, 0, 0);
            }
        }
        if (mrow < 4) {
            #pragma unroll
            for (int i = 0; i < 5; ++i) {
                const int rb = (wv * 5 + i) * 16 + q * 4;
                *(float4*)&gcat[mrow][rb] =
                    make_float4(acc[i].x, acc[i].y, acc[i].z, acc[i].w);
            }
        }
        __syncthreads();
        // ---- stage B ----
        if (upd) {
            float pi, pf, pg, po;
            if (L == 0) {
                pi = gcat[rw][kk]          + bi  + xi;
                pf = gcat[rw][H + kk]      + bff + xf;
                pg = gcat[rw][2 * H + kk]  + bg  + xg;
                po = gcat[rw][3 * H + kk]  + bo  + xo;
            } else {
                pi = gcat[rw][200 + kk]          + gcat[2 + rw][400 + kk]          + bi;
                pf = gcat[rw][200 + H + kk]      + gcat[2 + rw][400 + H + kk]      + bff;
                pg = gcat[rw][200 + 2 * H + kk]  + gcat[2 + rw][400 + 2 * H + kk]  + bg;
                po = gcat[rw][200 + 3 * H + kk]  + gcat[2 + rw][400 + 3 * H + kk]  + bo;
            }
            if (L == 0 || t > 0) {
                const float gi = sigm(pi), gf = sigm(pf);
                const float gg = tanhx(pg), go = sigm(po);
                c = gf * c + gi * gg;
                const float hv = go * tanhx(c);
                const short hh = bfhi(hv);
                Bhi[ncol][kk] = hh;
                Blo[ncol][kk] = bfhi(hv - bf2f(hh));
            }
            if (lx && t + 1 < TT) {   // prefetch next xp; hidden under next MFMA stage
                const float* xq = xpb + (size_t)(t + 1) * G4;
                xi = xq[kk]; xf = xq[H + kk]; xg = xq[2 * H + kk]; xo = xq[3 * H + kk];
            }
        }
        __syncthreads();
    }
    // ---- pipeline tail: gates1(TT-1) needs h0(TT-1) + h1(TT-2) (both in B now) ----
    {
        floatx4 acc[5];
        #pragma unroll
        for (int i = 0; i < 5; ++i) acc[i] = (floatx4)(0.0f);
        #pragma unroll
        for (int s = 0; s < 2; ++s) {
            const short8 bh = *(const short8*)&Bhi[mrow][s * 32 + q * 8];
            const short8 bl = *(const short8*)&Blo[mrow][s * 32 + q * 8];
            #pragma unroll
            for (int i = 0; i < 5; ++i) {
                acc[i] = __builtin_amdgcn_mfma_f32_16x16x32_bf16(Ahi[i][s], bh, acc[i], 0, 0, 0);
                acc[i] = __builtin_amdgcn_mfma_f32_16x16x32_bf16(Ahi[i][s], bl, acc[i], 0, 0, 0);
                acc[i] = __builtin_amdgcn_mfma_f32_16x16x32_bf16(Alo[i][s], bh, acc[i], 0, 0, 0);
            }
        }
        if (mrow < 4) {
            #pragma unroll
            for (int i = 0; i < 5; ++i) {
                const int rb = (wv * 5 + i) * 16 + q * 4;
                *(float4*)&gcat[mrow][rb] =
                    make_float4(acc[i].x, acc[i].y, acc[i].z, acc[i].w);
            }
        }
        __syncthreads();
        if (upd && L == 1) {
            const float pi = gcat[rw][200 + kk]         + gcat[2 + rw][400 + kk]         + bi;
            const float pf = gcat[rw][200 + H + kk]     + gcat[2 + rw][400 + H + kk]     + bff;
            const float pg = gcat[rw][200 + 2 * H + kk] + gcat[2 + rw][400 + 2 * H + kk] + bg;
            const float po = gcat[rw][200 + 3 * H + kk] + gcat[2 + rw][400 + 3 * H + kk] + bo;
            const float gi = sigm(pi), gf = sigm(pf);
            const float gg = tanhx(pg), go = sigm(po);
            c = gf * c + gi * gg;
            h1f[rw][kk] = go * tanhx(c);
        }
        __syncthreads();
    }
    // ---- fused FC on final hidden states ----
    if (tid < 2 * ODIM) {
        const int r = tid / ODIM;
        const int o = tid - r * ODIM;
        float s = bfc[o];
        const float* wr = Wfc + (size_t)o * H;
        #pragma unroll
        for (int k2 = 0; k2 < H; ++k2) s += wr[k2] * h1f[r][k2];
        out[(size_t)(b0 + r) * ODIM + o] = s;
    }
}

extern "C" void kernel_launch(void* const* d_in, const int* in_sizes, int n_in,
                              void* d_out, int out_size, void* d_ws, size_t ws_size,
                              hipStream_t stream) {
    const float* x    = (const float*)d_in[0];
    const float* wih0 = (const float*)d_in[1];
    const float* whh0 = (const float*)d_in[2];
    const float* bih0 = (const float*)d_in[3];
    const float* bhh0 = (const float*)d_in[4];
    const float* wih1 = (const float*)d_in[5];
    const float* whh1 = (const float*)d_in[6];
    const float* bih1 = (const float*)d_in[7];
    const float* bhh1 = (const float*)d_in[8];
    const float* wfc  = (const float*)d_in[9];
    const float* bfc  = (const float*)d_in[10];
    float* outp = (float*)d_out;
    float* XP = (float*)d_ws;   // 131072 x 200 fp32 = 104.86 MB scratch

    dim3 g1(BATCH * TT / BM, (G4 + BN - 1) / BN);   // (2048, 4)
    xproj_gemm<<<g1, 256, 0, stream>>>(x, wih0, XP);
    lstm_mfma<<<BATCH / 2, 512, 0, stream>>>(XP, whh0, wih1, whh1,
                                             bih0, bhh0, bih1, bhh1,
                                             wfc, bfc, outp);
}